// Round 14
// baseline (392.778 us; speedup 1.0000x reference)
//
#include <hip/hip_runtime.h>
#include <stdint.h>

// ---------------------------------------------------------------------------
// Speaker pairwise loss. R14 = R8 core (circulant-band half matrix, 512 equal
// blocks of 4-5 tiles, register-resident row stats, per-wave-half partial
// stores -- proven 61.8us/pass) with the reduce kernels FOLDED INTO the pair
// kernels via per-strip completion tickets:
//   each block, after storing partials + __threadfence(), atomicAdds the
//   counter of every strip it contributed to (<=6). Whoever lands the final
//   ticket for a strip runs that strip's reduction inline (no spinning, no
//   extra blocks, no coop launch -> no deadlock surface). 5 dispatches -> 3.
// R13 lesson: sim materialization (138MB fp32) is SLOWER than recompute.
// R11: more blocks don't help (capacity-capped ~2/CU). R10: no coop launch.
// R7: imbalance kills. R6: dbuf neutral. R5: no min-waves bound.
// ws: fb bf16[B*D] | rp0/rp1[512*256] | cp0/cp1[64*33*256] | tmn[B] tmx[B]
//     | cnt1[64] cnt2[64]
// ---------------------------------------------------------------------------

typedef __attribute__((ext_vector_type(8))) short short8;   // 8 bf16
typedef __attribute__((ext_vector_type(4))) float floatx4;  // MFMA C/D

constexpr int D = 256;
constexpr int BM = 128;
constexpr int NT = 64;                    // 8192/128 strips
constexpr int NPB = 512;                  // pair blocks (64 strips x 8)
constexpr int CPS = 33;                   // cp slots per strip (off 0..32)

__device__ __forceinline__ unsigned f2bf(float f) {  // fp32 -> bf16, RNE
  unsigned u = __float_as_uint(f);
  return (u + 0x7FFFu + ((u >> 16) & 1u)) >> 16;
}

__device__ __forceinline__ void gl_lds16(const void* g, void* l) {
  __builtin_amdgcn_global_load_lds(
      (const __attribute__((address_space(1))) unsigned int*)g,
      (__attribute__((address_space(3))) unsigned int*)l, 16, 0, 0);
}

// number of producer blocks contributing to strip T: 8 row blocks + col blocks
__device__ int stripExpected(int T) {
  int c = 8;
  for (int I = 0; I < NT; ++I) {
    int off = (T - I) & 63;
    int lim = (I < 32) ? 32 : 31;
    c += (off >= 1 && off <= lim) ? 1 : 0;
  }
  return c;
}

__global__ void convert_kernel(const float* __restrict__ feats,
                               unsigned short* __restrict__ fb, int n4,
                               float* __restrict__ out,
                               int* __restrict__ cnt1, int* __restrict__ cnt2) {
  int i = blockIdx.x * blockDim.x + threadIdx.x;
  if (i < n4) {
    float4 v = ((const float4*)feats)[i];
    unsigned lo = f2bf(v.x) | (f2bf(v.y) << 16);
    unsigned hi = f2bf(v.z) | (f2bf(v.w) << 16);
    ((uint2*)fb)[i] = make_uint2(lo, hi);
  }
  if (blockIdx.x == 0) {
    if (threadIdx.x < NT) { cnt1[threadIdx.x] = 0; cnt2[threadIdx.x] = 0; }
    if (threadIdx.x == 0) { out[0] = 0.f; out[1] = 1.f; }
  }
}

// fold partials for strip T (called inline by the last-finishing block)
template <int PASS>
__device__ void reduce_body(
    int T, const float* __restrict__ rp0, const float* __restrict__ rp1,
    const float* __restrict__ cp0, const float* __restrict__ cp1,
    float* __restrict__ o0, float* __restrict__ o1, float* __restrict__ out,
    float* sA, float* sB, float* sred) {
  const int q = threadIdx.x & 127;
  const int h = threadIdx.x >> 7;

  float a = (PASS == 1) ? __builtin_inff() : 0.f;
  float b = (PASS == 1) ? -__builtin_inff() : 0.f;
#pragma unroll
  for (int g = 0; g < 8; ++g) {
    size_t o = (size_t)(T * 8 + g) * 256 + (size_t)h * 128 + q;
    float v0 = rp0[o], v1 = rp1[o];
    a = (PASS == 1) ? fminf(a, v0) : (a + v0);
    b = (PASS == 1) ? fmaxf(b, v1) : (b + v1);
  }
  for (int I = 0; I < NT; ++I) {
    int off = (T - I) & 63;
    int lim = (I < 32) ? 32 : 31;
    if (off >= 1 && off <= lim) {
      size_t o = (size_t)(I * CPS + off) * 256 + (size_t)h * 128 + q;
      float v0 = cp0[o], v1 = cp1[o];
      a = (PASS == 1) ? fminf(a, v0) : (a + v0);
      b = (PASS == 1) ? fmaxf(b, v1) : (b + v1);
    }
  }
  if (h == 1) { sA[q] = a; sB[q] = b; }
  __syncthreads();
  if (h == 0) {
    a = (PASS == 1) ? fminf(a, sA[q]) : (a + sA[q]);
    b = (PASS == 1) ? fmaxf(b, sB[q]) : (b + sB[q]);
    if (PASS == 1) {
      o0[T * 128 + q] = a - 0.1f;   // min_pos - MARGIN (inf-safe)
      o1[T * 128 + q] = b + 0.1f;   // max_neg + MARGIN
    } else {
      float loss = 0.f, cnt = 0.f;
      if (a > 0.f && b > 0.f) {
        loss = 0.5f * log1pf(a) + 0.02f * log1pf(b);
        cnt = 1.f;
      }
#pragma unroll
      for (int m = 1; m < 64; m <<= 1) {
        loss += __shfl_xor(loss, m);
        cnt  += __shfl_xor(cnt, m);
      }
      int wv = threadIdx.x >> 6, ln = threadIdx.x & 63;
      if (ln == 0) { sred[wv] = loss; sred[4 + wv] = cnt; }
    }
  }
  if (PASS == 2) {
    __syncthreads();
    if (threadIdx.x == 0) {
      float L = sred[0] + sred[1];
      float C = sred[4] + sred[5];
      atomicAdd(out, L / 8192.0f);
      atomicAdd(out + 1, -C / 8192.0f);
    }
  }
}

template <int PASS>
__global__ __launch_bounds__(256)
void pair_kernel(const unsigned short* __restrict__ fb, const int* __restrict__ labels,
                 const float* __restrict__ tmn, const float* __restrict__ tmx,
                 float* __restrict__ rp0, float* __restrict__ rp1,
                 float* __restrict__ cp0, float* __restrict__ cp1,
                 int* __restrict__ cnt, float* __restrict__ o0,
                 float* __restrict__ o1, float* __restrict__ out) {
  __shared__ __align__(16) short As[BM * 64];   // 16KB
  __shared__ __align__(16) short Bs[BM * 64];   // 16KB
  __shared__ int   labA[BM];
  __shared__ float tA0[BM], tA1[BM];
  __shared__ int   doneStrips[8];
  __shared__ int   nDone;

  const int bid = blockIdx.x;
  const int I   = bid >> 3;                 // strip (fixed per block)
  const int g   = bid & 7;
  const int nT  = (I < 32) ? 33 : 32;       // tiles in strip
  const int t0  = (g * nT) >> 3;
  const int t1  = ((g + 1) * nT) >> 3;      // 4 or 5 tiles
  const int row0 = I * BM;

  const int tid  = threadIdx.x;
  const int lane = tid & 63;
  const int wave = tid >> 6;
  const int l15  = lane & 15;
  const int quad = lane >> 4;
  const int wr   = (wave >> 1) * 64;
  const int wc   = (wave & 1) * 64;

  const float ONE_EPS = 1.0f - 1e-5f;
  const float INF = __builtin_inff();

  const int srow = (wave << 5) + (lane >> 3);   // staging: 8 lanes/row, 16B/lane
  const int slot = lane & 7;

  auto stage = [&](int kc, int col0) {
#pragma unroll
    for (int j = 0; j < 4; ++j) {
      int r = srow + 8 * j;
      int sw = (slot ^ (r & 7)) << 4;           // XOR swizzle (0 conflicts)
      const char* ga = (const char*)fb + (((size_t)(row0 + r)) << 9) + (kc << 7) + sw;
      const char* gb = (const char*)fb + (((size_t)(col0 + r)) << 9) + (kc << 7) + sw;
      gl_lds16(ga, (char*)As + (r << 7) + (slot << 4));
      gl_lds16(gb, (char*)Bs + (r << 7) + (slot << 4));
    }
  };

  if (tid < BM) {                               // once per block (covered by 1st sync)
    labA[tid] = labels[row0 + tid];
    if (PASS == 2) { tA0[tid] = tmn[row0 + tid]; tA1[tid] = tmx[row0 + tid]; }
  }

  int arow[4], brow[4];
#pragma unroll
  for (int i = 0; i < 4; ++i) {
    arow[i] = wr + i * 16 + l15;
    brow[i] = wc + i * 16 + l15;
  }

  // row stats: live in registers across the whole block
  float s0[16], s1[16];
#pragma unroll
  for (int i = 0; i < 16; ++i) {
    s0[i] = (PASS == 1) ? INF : 0.f;
    s1[i] = (PASS == 1) ? -INF : 0.f;
  }

  for (int off = t0; off < t1; ++off) {
    const int J = (I + off) & 63;
    const int col0 = J * BM;
    const bool diag = (off == 0);

    floatx4 acc[4][4];
#pragma unroll
    for (int rf = 0; rf < 4; ++rf)
#pragma unroll
      for (int cf = 0; cf < 4; ++cf)
        acc[rf][cf] = (floatx4)(0.f);

    for (int kc = 0; kc < 4; ++kc) {
      stage(kc, col0);
      __syncthreads();
#pragma unroll
      for (int ks = 0; ks < 2; ++ks) {
        const int gg = ks * 4 + quad;
        short8 a[4], b[4];
#pragma unroll
        for (int rf = 0; rf < 4; ++rf)
          a[rf] = *(const short8*)(As + arow[rf] * 64 + ((gg ^ (arow[rf] & 7)) << 3));
#pragma unroll
        for (int cf = 0; cf < 4; ++cf)
          b[cf] = *(const short8*)(Bs + brow[cf] * 64 + ((gg ^ (brow[cf] & 7)) << 3));
#pragma unroll
        for (int rf = 0; rf < 4; ++rf)
#pragma unroll
          for (int cf = 0; cf < 4; ++cf)
            acc[rf][cf] = __builtin_amdgcn_mfma_f32_16x16x32_bf16(a[rf], b[cf], acc[rf][cf], 0, 0, 0);
      }
      __syncthreads();
    }

    // col labels/thresholds (L1/L2-hot)
    int labc[4];
    float tBn[4], tBx[4];
#pragma unroll
    for (int cf = 0; cf < 4; ++cf) {
      int ci = col0 + wc + cf * 16 + l15;
      labc[cf] = labels[ci];
      if (PASS == 2) { tBn[cf] = tmn[ci]; tBx[cf] = tmx[ci]; }
    }

    float c0[4], c1[4];
#pragma unroll
    for (int i = 0; i < 4; ++i) {
      c0[i] = (PASS == 1) ? INF : 0.f;
      c1[i] = (PASS == 1) ? -INF : 0.f;
    }

#pragma unroll
    for (int rf = 0; rf < 4; ++rf) {
#pragma unroll
      for (int r = 0; r < 4; ++r) {
        const int ri = wr + rf * 16 + quad * 4 + r;
        const int lr = labA[ri];
        float tRn = 0.f, tRx = 0.f;
        if (PASS == 2) { tRn = tA0[ri]; tRx = tA1[ri]; }
#pragma unroll
        for (int cf = 0; cf < 4; ++cf) {
          float sim = acc[rf][cf][r];
          bool same = (lr == labc[cf]);
          bool posok = same && (sim < ONE_EPS);
          if (PASS == 1) {
            float pc = posok ? sim : INF;
            float nc = same ? -INF : sim;
            s0[rf * 4 + r] = fminf(s0[rf * 4 + r], pc);
            s1[rf * 4 + r] = fmaxf(s1[rf * 4 + r], nc);
            c0[cf] = fminf(c0[cf], pc);
            c1[cf] = fmaxf(c1[cf], nc);
          } else {
            if (posok) {
              float e = __expf(fmaf(-2.f, sim, 1.f));
              if (sim < tRx)      s0[rf * 4 + r] += e;
              if (sim < tBx[cf])  c0[cf] += e;
            } else if (!same) {
              float e = (sim > 0.22f) ? __expf(fmaf(50.f, sim, -25.f)) : 0.f;
              if (sim > tRn)      s1[rf * 4 + r] += 1e-30f + e;
              if (sim > tBn[cf])  c1[cf] += 1e-30f + e;
            }
          }
        }
      }
    }

    // col flush per tile: reduce over quads, store per wave-half
    if (!diag) {
#pragma unroll
      for (int cf = 0; cf < 4; ++cf) {
        float v = c0[cf], w = c1[cf];
#pragma unroll
        for (int m = 16; m < 64; m <<= 1) {
          float vv = __shfl_xor(v, m), ww = __shfl_xor(w, m);
          v = (PASS == 1) ? fminf(v, vv) : (v + vv);
          w = (PASS == 1) ? fmaxf(w, ww) : (w + ww);
        }
        if (quad == 0) {
          size_t o = (size_t)(I * CPS + off) * 256 + (size_t)(wr >> 6) * 128 + wc + cf * 16 + l15;
          cp0[o] = v;
          cp1[o] = w;
        }
      }
    }
  }

  // row flush once per block: reduce over l15, store per wave-half
#pragma unroll
  for (int i = 0; i < 16; ++i) {
#pragma unroll
    for (int m = 1; m < 16; m <<= 1) {
      float v = __shfl_xor(s0[i], m), w = __shfl_xor(s1[i], m);
      s0[i] = (PASS == 1) ? fminf(s0[i], v) : (s0[i] + v);
      s1[i] = (PASS == 1) ? fmaxf(s1[i], w) : (s1[i] + w);
    }
  }
  if (l15 == 0) {
#pragma unroll
    for (int rf = 0; rf < 4; ++rf)
#pragma unroll
      for (int r = 0; r < 4; ++r) {
        int ri = wr + rf * 16 + quad * 4 + r;
        size_t o = (size_t)bid * 256 + (size_t)(wc >> 6) * 128 + ri;
        rp0[o] = s0[rf * 4 + r];
        rp1[o] = s1[rf * 4 + r];
      }
  }

  // ---- completion tickets: last contributor to a strip reduces it inline ----
  __threadfence();                              // release partial stores
  if (tid == 0) {
    int nd = 0;
    int prev = atomicAdd(cnt + I, 1);           // row contribution -> strip I
    if (prev == stripExpected(I) - 1) doneStrips[nd++] = I;
    for (int off = t0; off < t1; ++off) {
      if (off < 1) continue;                    // diag tile has no col store
      int T = (I + off) & 63;
      prev = atomicAdd(cnt + T, 1);
      if (prev == stripExpected(T) - 1) doneStrips[nd++] = T;
    }
    nDone = nd;
  }
  __syncthreads();
  for (int k = 0; k < nDone; ++k) {
    __threadfence();                            // acquire other blocks' stores
    reduce_body<PASS>(doneStrips[k], rp0, rp1, cp0, cp1, o0, o1, out,
                      (float*)As, (float*)As + 128, (float*)As + 256);
    __syncthreads();                            // shared scratch reuse between strips
  }
}

extern "C" void kernel_launch(void* const* d_in, const int* in_sizes, int n_in,
                              void* d_out, int out_size, void* d_ws, size_t ws_size,
                              hipStream_t stream) {
  const float* feats  = (const float*)d_in[0];
  const int*   labels = (const int*)d_in[1];
  const int Bn = in_sizes[1];          // 8192
  float* out = (float*)d_out;

  unsigned short* fb = (unsigned short*)d_ws;                       // 4 MB
  float* rp0 = (float*)((char*)d_ws + (size_t)Bn * D * 2);
  float* rp1 = rp0 + (size_t)NPB * 256;
  float* cp0 = rp1 + (size_t)NPB * 256;
  float* cp1 = cp0 + (size_t)NT * CPS * 256;
  float* tmn = cp1 + (size_t)NT * CPS * 256;
  float* tmx = tmn + Bn;
  int*   cnt1 = (int*)(tmx + Bn);
  int*   cnt2 = cnt1 + NT;

  int n4 = Bn * D / 4;
  convert_kernel<<<(n4 + 255) / 256, 256, 0, stream>>>(feats, fb, n4, out, cnt1, cnt2);

  pair_kernel<1><<<NPB, 256, 0, stream>>>(fb, labels, nullptr, nullptr,
                                          rp0, rp1, cp0, cp1, cnt1, tmn, tmx, out);
  pair_kernel<2><<<NPB, 256, 0, stream>>>(fb, labels, tmn, tmx,
                                          rp0, rp1, cp0, cp1, cnt2, nullptr, nullptr, out);
}

// Round 15
// 216.112 us; speedup vs baseline: 1.8175x; 1.8175x over previous
//
#include <hip/hip_runtime.h>
#include <stdint.h>

// ---------------------------------------------------------------------------
// Speaker pairwise loss. R15: attack the pair kernel's latency chain.
// R8 analysis: per CU/pass ~15us VALU + ~5us MFMA + ~40us IDLE -- the
// per-chunk stage->barrier(vmcnt0)->MFMA->barrier chain exposes load latency
// 4x/tile. Restructure:
//  - A tile is strip-invariant: staged ONCE per block, full-K in LDS (64KB).
//  - B full-K (64KB) per tile; K-loop = 8 barrier-free MFMA iterations.
//  - REGISTER PREFETCH of B(t+1) (16x global_load_dwordx4 -> 64 VGPR) issued
//    right after B(t) is published; lands during tile-t compute; next tile
//    starts with 16 ds_write_b128 (cheap). 2 barriers/tile (was 8).
//  - LDS ~131KB -> 1 block/CU (4 waves, 1 wave/SIMD -> VGPR budget 512, no
//    spill risk from the 64 pf regs). Grid = 256 equal blocks (64 strips x 4
//    groups of 8-9 tiles), exactly 1 block/CU.
// Kept: circulant band, register row stats, per-wave-half partial stores,
// separate tiny reduce kernels (R14: in-kernel sync/threadfence = 2x poison;
// R10: no coop; R13: no materialization; R5: no min-waves bound).
// ws: fb bf16[B*D] | rp0/rp1[256*256] | cp0/cp1[64*33*256] | tmn[B] tmx[B]
// ---------------------------------------------------------------------------

typedef __attribute__((ext_vector_type(8))) short short8;     // 8 bf16
typedef __attribute__((ext_vector_type(4))) float floatx4;    // MFMA C/D
typedef __attribute__((ext_vector_type(4))) unsigned int uintx4;

constexpr int D = 256;
constexpr int BM = 128;
constexpr int NT = 64;                    // 8192/128 strips
constexpr int GPS = 4;                    // groups per strip
constexpr int NPB = NT * GPS;             // 256 pair blocks (1 per CU)
constexpr int CPS = 33;                   // cp slots per strip (off 0..32)

__device__ __forceinline__ unsigned f2bf(float f) {  // fp32 -> bf16, RNE
  unsigned u = __float_as_uint(f);
  return (u + 0x7FFFu + ((u >> 16) & 1u)) >> 16;
}

__device__ __forceinline__ void gl_lds16(const void* g, void* l) {
  __builtin_amdgcn_global_load_lds(
      (const __attribute__((address_space(1))) unsigned int*)g,
      (__attribute__((address_space(3))) unsigned int*)l, 16, 0, 0);
}

__global__ void convert_kernel(const float* __restrict__ feats,
                               unsigned short* __restrict__ fb, int n4,
                               float* __restrict__ out) {
  int i = blockIdx.x * blockDim.x + threadIdx.x;
  if (i < n4) {
    float4 v = ((const float4*)feats)[i];
    unsigned lo = f2bf(v.x) | (f2bf(v.y) << 16);
    unsigned hi = f2bf(v.z) | (f2bf(v.w) << 16);
    ((uint2*)fb)[i] = make_uint2(lo, hi);
  }
  if (blockIdx.x == 0 && threadIdx.x == 0) { out[0] = 0.f; out[1] = 1.f; }
}

template <int PASS>
__global__ __launch_bounds__(256)
void pair_kernel(const unsigned short* __restrict__ fb, const int* __restrict__ labels,
                 const float* __restrict__ tmn, const float* __restrict__ tmx,
                 float* __restrict__ rp0, float* __restrict__ rp1,
                 float* __restrict__ cp0, float* __restrict__ cp1) {
  __shared__ __align__(16) short As[BM * 256];   // 64KB, full-K, strip-resident
  __shared__ __align__(16) short Bs[BM * 256];   // 64KB, full-K, per tile
  __shared__ int   labA[BM];
  __shared__ float tA0[BM], tA1[BM];

  const int bid = blockIdx.x;
  const int I   = bid >> 2;                 // strip (fixed per block)
  const int g   = bid & 3;
  const int nT  = (I < 32) ? 33 : 32;       // tiles in strip
  const int t0  = (g * nT) >> 2;
  const int t1  = ((g + 1) * nT) >> 2;      // 8 or 9 tiles
  const int row0 = I * BM;

  const int tid  = threadIdx.x;
  const int lane = tid & 63;
  const int wave = tid >> 6;
  const int l15  = lane & 15;
  const int quad = lane >> 4;
  const int wr   = (wave >> 1) * 64;
  const int wc   = (wave & 1) * 64;

  const float ONE_EPS = 1.0f - 1e-5f;
  const float INF = __builtin_inff();

  // staging map (full-K rows of 512B = 32 x 16B slots, XOR-32 swizzle):
  // issue i: LDS byte off = i*4096 + tid*16  (= wave-uniform base + lane*16)
  //          row = 8i + (tid>>5), slot = tid&31, global group = slot^(row&31)
  const int srow5 = tid >> 5;
  const int slot  = tid & 31;

  // ---- one-time stage: A (strip) + B(first tile) via global_load_lds ----
  const int J0col = ((I + t0) & 63) * BM;
#pragma unroll
  for (int i = 0; i < 16; ++i) {
    int row = 8 * i + srow5;
    int gg  = slot ^ (row & 31);
    int off = (i << 12) + (tid << 4);
    gl_lds16((const char*)fb + (((size_t)(row0 + row)) << 9) + (gg << 4), (char*)As + off);
    gl_lds16((const char*)fb + (((size_t)(J0col + row)) << 9) + (gg << 4), (char*)Bs + off);
  }
  if (tid < BM) {
    labA[tid] = labels[row0 + tid];
    if (PASS == 2) { tA0[tid] = tmn[row0 + tid]; tA1[tid] = tmx[row0 + tid]; }
  }
  __syncthreads();

  int arow[4], brow[4];
#pragma unroll
  for (int i = 0; i < 4; ++i) {
    arow[i] = wr + i * 16 + l15;
    brow[i] = wc + i * 16 + l15;
  }

  float s0[16], s1[16];
#pragma unroll
  for (int i = 0; i < 16; ++i) {
    s0[i] = (PASS == 1) ? INF : 0.f;
    s1[i] = (PASS == 1) ? -INF : 0.f;
  }

  uintx4 pf[16];                            // B(t+1) prefetch registers

  for (int off = t0; off < t1; ++off) {
    const int J = (I + off) & 63;
    const int col0 = J * BM;
    const bool diag = (off == 0);

    if (off > t0) {
      // publish prefetched B(t) to LDS, then barrier
#pragma unroll
      for (int i = 0; i < 16; ++i)
        *(uintx4*)((char*)Bs + (i << 12) + (tid << 4)) = pf[i];
      __syncthreads();
    }
    if (off + 1 < t1) {
      // issue B(t+1) loads now; they land during this tile's compute
      const int cn = ((I + off + 1) & 63) * BM;
#pragma unroll
      for (int i = 0; i < 16; ++i) {
        int row = 8 * i + srow5;
        int gg  = slot ^ (row & 31);
        pf[i] = *(const uintx4*)((const char*)fb + (((size_t)(cn + row)) << 9) + (gg << 4));
      }
    }

    // ---- K loop: 8 iterations, no barriers (A,B full-K resident) ----
    floatx4 acc[4][4];
#pragma unroll
    for (int rf = 0; rf < 4; ++rf)
#pragma unroll
      for (int cf = 0; cf < 4; ++cf)
        acc[rf][cf] = (floatx4)(0.f);

#pragma unroll
    for (int ks = 0; ks < 8; ++ks) {
      const int gg = ks * 4 + quad;         // 16B group 0..31
      short8 a[4], b[4];
#pragma unroll
      for (int rf = 0; rf < 4; ++rf)
        a[rf] = *(const short8*)((const char*)As + (arow[rf] << 9) + ((gg ^ (arow[rf] & 31)) << 4));
#pragma unroll
      for (int cf = 0; cf < 4; ++cf)
        b[cf] = *(const short8*)((const char*)Bs + (brow[cf] << 9) + ((gg ^ (brow[cf] & 31)) << 4));
#pragma unroll
      for (int rf = 0; rf < 4; ++rf)
#pragma unroll
        for (int cf = 0; cf < 4; ++cf)
          acc[rf][cf] = __builtin_amdgcn_mfma_f32_16x16x32_bf16(a[rf], b[cf], acc[rf][cf], 0, 0, 0);
    }

    // col labels/thresholds (L1/L2-hot)
    int labc[4];
    float tBn[4], tBx[4];
#pragma unroll
    for (int cf = 0; cf < 4; ++cf) {
      int ci = col0 + wc + cf * 16 + l15;
      labc[cf] = labels[ci];
      if (PASS == 2) { tBn[cf] = tmn[ci]; tBx[cf] = tmx[ci]; }
    }

    float c0[4], c1[4];
#pragma unroll
    for (int i = 0; i < 4; ++i) {
      c0[i] = (PASS == 1) ? INF : 0.f;
      c1[i] = (PASS == 1) ? -INF : 0.f;
    }

#pragma unroll
    for (int rf = 0; rf < 4; ++rf) {
#pragma unroll
      for (int r = 0; r < 4; ++r) {
        const int ri = wr + rf * 16 + quad * 4 + r;
        const int lr = labA[ri];
        float tRn = 0.f, tRx = 0.f;
        if (PASS == 2) { tRn = tA0[ri]; tRx = tA1[ri]; }
#pragma unroll
        for (int cf = 0; cf < 4; ++cf) {
          float sim = acc[rf][cf][r];
          bool same = (lr == labc[cf]);
          bool posok = same && (sim < ONE_EPS);
          if (PASS == 1) {
            float pc = posok ? sim : INF;
            float nc = same ? -INF : sim;
            s0[rf * 4 + r] = fminf(s0[rf * 4 + r], pc);
            s1[rf * 4 + r] = fmaxf(s1[rf * 4 + r], nc);
            c0[cf] = fminf(c0[cf], pc);
            c1[cf] = fmaxf(c1[cf], nc);
          } else {
            if (posok) {
              float e = __expf(fmaf(-2.f, sim, 1.f));
              if (sim < tRx)      s0[rf * 4 + r] += e;
              if (sim < tBx[cf])  c0[cf] += e;
            } else if (!same) {
              float e = (sim > 0.22f) ? __expf(fmaf(50.f, sim, -25.f)) : 0.f;
              if (sim > tRn)      s1[rf * 4 + r] += 1e-30f + e;
              if (sim > tBn[cf])  c1[cf] += 1e-30f + e;
            }
          }
        }
      }
    }

    // col flush per tile: reduce over quads, store per wave-half
    if (!diag) {
#pragma unroll
      for (int cf = 0; cf < 4; ++cf) {
        float v = c0[cf], w = c1[cf];
#pragma unroll
        for (int m = 16; m < 64; m <<= 1) {
          float vv = __shfl_xor(v, m), ww = __shfl_xor(w, m);
          v = (PASS == 1) ? fminf(v, vv) : (v + vv);
          w = (PASS == 1) ? fmaxf(w, ww) : (w + ww);
        }
        if (quad == 0) {
          size_t o = (size_t)(I * CPS + off) * 256 + (size_t)(wr >> 6) * 128 + wc + cf * 16 + l15;
          cp0[o] = v;
          cp1[o] = w;
        }
      }
    }

    __syncthreads();   // Bs fully consumed; safe to overwrite next iteration
  }

  // row flush once per block: reduce over l15, store per wave-half
#pragma unroll
  for (int i = 0; i < 16; ++i) {
#pragma unroll
    for (int m = 1; m < 16; m <<= 1) {
      float v = __shfl_xor(s0[i], m), w = __shfl_xor(s1[i], m);
      s0[i] = (PASS == 1) ? fminf(s0[i], v) : (s0[i] + v);
      s1[i] = (PASS == 1) ? fmaxf(s1[i], w) : (s1[i] + w);
    }
  }
  if (l15 == 0) {
#pragma unroll
    for (int rf = 0; rf < 4; ++rf)
#pragma unroll
      for (int r = 0; r < 4; ++r) {
        int ri = wr + rf * 16 + quad * 4 + r;
        size_t o = (size_t)bid * 256 + (size_t)(wc >> 6) * 128 + ri;
        rp0[o] = s0[rf * 4 + r];
        rp1[o] = s1[rf * 4 + r];
      }
  }
}

// fold partials for strip T: 4 row blocks (bid=T*4+g) + col slots (I,off)
// with (I+off)%64==T, 1<=off<=lim(I). PASS1 -> thresholds; PASS2 -> loss.
template <int PASS>
__global__ void reduce_kernel(const float* __restrict__ rp0, const float* __restrict__ rp1,
                              const float* __restrict__ cp0, const float* __restrict__ cp1,
                              float* __restrict__ o0, float* __restrict__ o1,
                              float* __restrict__ out) {
  __shared__ float sA[128], sB[128], sred[8];
  const int T = blockIdx.x;            // 64 strips
  const int q = threadIdx.x & 127;
  const int h = threadIdx.x >> 7;      // wave-half selector

  float a = (PASS == 1) ? __builtin_inff() : 0.f;
  float b = (PASS == 1) ? -__builtin_inff() : 0.f;
#pragma unroll
  for (int g = 0; g < GPS; ++g) {
    size_t o = (size_t)(T * GPS + g) * 256 + (size_t)h * 128 + q;
    float v0 = rp0[o], v1 = rp1[o];
    a = (PASS == 1) ? fminf(a, v0) : (a + v0);
    b = (PASS == 1) ? fmaxf(b, v1) : (b + v1);
  }
  for (int I = 0; I < NT; ++I) {
    int off = (T - I) & 63;
    int lim = (I < 32) ? 32 : 31;
    if (off >= 1 && off <= lim) {
      size_t o = (size_t)(I * CPS + off) * 256 + (size_t)h * 128 + q;
      float v0 = cp0[o], v1 = cp1[o];
      a = (PASS == 1) ? fminf(a, v0) : (a + v0);
      b = (PASS == 1) ? fmaxf(b, v1) : (b + v1);
    }
  }
  if (h == 1) { sA[q] = a; sB[q] = b; }
  __syncthreads();
  if (h == 0) {
    a = (PASS == 1) ? fminf(a, sA[q]) : (a + sA[q]);
    b = (PASS == 1) ? fmaxf(b, sB[q]) : (b + sB[q]);
    if (PASS == 1) {
      o0[T * 128 + q] = a - 0.1f;   // min_pos - MARGIN (inf-safe)
      o1[T * 128 + q] = b + 0.1f;   // max_neg + MARGIN
    } else {
      float loss = 0.f, cnt = 0.f;
      if (a > 0.f && b > 0.f) {
        loss = 0.5f * log1pf(a) + 0.02f * log1pf(b);
        cnt = 1.f;
      }
#pragma unroll
      for (int m = 1; m < 64; m <<= 1) {
        loss += __shfl_xor(loss, m);
        cnt  += __shfl_xor(cnt, m);
      }
      int wv = threadIdx.x >> 6, ln = threadIdx.x & 63;
      if (ln == 0) { sred[wv] = loss; sred[4 + wv] = cnt; }
    }
  }
  if (PASS == 2) {
    __syncthreads();
    if (threadIdx.x == 0) {
      float L = sred[0] + sred[1];
      float C = sred[4] + sred[5];
      atomicAdd(out, L / 8192.0f);
      atomicAdd(out + 1, -C / 8192.0f);
    }
  }
}

extern "C" void kernel_launch(void* const* d_in, const int* in_sizes, int n_in,
                              void* d_out, int out_size, void* d_ws, size_t ws_size,
                              hipStream_t stream) {
  const float* feats  = (const float*)d_in[0];
  const int*   labels = (const int*)d_in[1];
  const int Bn = in_sizes[1];          // 8192
  float* out = (float*)d_out;

  unsigned short* fb = (unsigned short*)d_ws;                       // 4 MB
  float* rp0 = (float*)((char*)d_ws + (size_t)Bn * D * 2);
  float* rp1 = rp0 + (size_t)NPB * 256;
  float* cp0 = rp1 + (size_t)NPB * 256;
  float* cp1 = cp0 + (size_t)NT * CPS * 256;
  float* tmn = cp1 + (size_t)NT * CPS * 256;
  float* tmx = tmn + Bn;

  int n4 = Bn * D / 4;
  convert_kernel<<<(n4 + 255) / 256, 256, 0, stream>>>(feats, fb, n4, out);

  pair_kernel<1><<<NPB, 256, 0, stream>>>(fb, labels, nullptr, nullptr, rp0, rp1, cp0, cp1);
  reduce_kernel<1><<<NT, 256, 0, stream>>>(rp0, rp1, cp0, cp1, tmn, tmx, out);
  pair_kernel<2><<<NPB, 256, 0, stream>>>(fb, labels, tmn, tmx, rp0, rp1, cp0, cp1);
  reduce_kernel<2><<<NT, 256, 0, stream>>>(rp0, rp1, cp0, cp1, nullptr, nullptr, out);
}